// Round 1
// baseline (4690.018 us; speedup 1.0000x reference)
//
#include <hip/hip_runtime.h>
#include <cstddef>

// LSTM_27934467293427 — fused persistent-recurrence kernel.
// Structure: 1 block per batch element (grid=256 ~ 1 block/CU), 256 threads.
// Thread t: quarter q=t&3 of the 192-long dot for gates (t>>2)*4 + 0..3.
// Weights live in registers (~310 VGPR/thread, 1 wave/SIMD, 4 waves = CU full).
// h double-buffered in LDS; gates staged through LDS; x_{t+1} register-prefetched.
// Head (K=13, H2=2) computed one step lagged, reusing the h-chunk regs.
// Early exit at len[b] — output only depends on steps < len.

namespace {

constexpr int B_ = 256;
constexpr int S_ = 2048;
constexpr int E_ = 128;
constexpr int H_ = 64;
constexpr int G_ = 256;   // 4*H
constexpr int H2_ = 2;
constexpr int NTHR = 256;
constexpr int KO4_ = 104; // 26 head outputs * 4 lanes

__device__ __forceinline__ float sigm(float x) {
    return __builtin_amdgcn_rcpf(1.0f + __expf(-x));
}
__device__ __forceinline__ float tanh_fast(float x) {
    // tanh(x) = 1 - 2/(1+exp(2x)); exact at +-inf, ~1e-6 rel err.
    return 1.0f - 2.0f * __builtin_amdgcn_rcpf(1.0f + __expf(2.0f * x));
}
__device__ __forceinline__ float dot4(float4 a, float4 b) {
    return a.x * b.x + a.y * b.y + a.z * b.z + a.w * b.w;
}

__device__ __forceinline__ void lstm_step(
    int u, int len, int t, int q, int gb, int b,
    const float4 (&wx)[4][8], const float4 (&wh)[4][4],
    const float4 (&wk)[4], float whh0, float whh1, float hbsum, float bsum,
    float& hk, float& c,
    const float4 (&xcur)[8], float4 (&xnxt)[8],
    const float4* xp0,
    float (*h_lds)[H_], float* g_lds, float* __restrict__ out)
{
    const bool do_lstm = (u < len);

    // ---- prefetch x_{u+1} (no dependence on this step) ----
    if (u + 1 < len) {
        #pragma unroll
        for (int e = 0; e < 8; ++e)
            xnxt[e] = xp0[(size_t)(u + 1) * (E_ / 4) + e];
    }

    // ---- h_{u-1} chunk for this thread's quarter (broadcast-friendly b128s) ----
    const float4* hrow = (const float4*)h_lds[(u + 1) & 1];
    const float4 hv0 = hrow[q * 4 + 0];
    const float4 hv1 = hrow[q * 4 + 1];
    const float4 hv2 = hrow[q * 4 + 2];
    const float4 hv3 = hrow[q * 4 + 3];

    // ---- gate partial dots: 4 gates x (32 x-elems + 16 h-elems) ----
    if (do_lstm) {
        float p0 = 0.f, p1 = 0.f, p2 = 0.f, p3 = 0.f;
        #pragma unroll
        for (int e = 0; e < 8; ++e) {
            p0 += dot4(wx[0][e], xcur[e]);
            p1 += dot4(wx[1][e], xcur[e]);
            p2 += dot4(wx[2][e], xcur[e]);
            p3 += dot4(wx[3][e], xcur[e]);
        }
        p0 += dot4(wh[0][0], hv0) + dot4(wh[0][1], hv1) + dot4(wh[0][2], hv2) + dot4(wh[0][3], hv3);
        p1 += dot4(wh[1][0], hv0) + dot4(wh[1][1], hv1) + dot4(wh[1][2], hv2) + dot4(wh[1][3], hv3);
        p2 += dot4(wh[2][0], hv0) + dot4(wh[2][1], hv1) + dot4(wh[2][2], hv2) + dot4(wh[2][3], hv3);
        p3 += dot4(wh[3][0], hv0) + dot4(wh[3][1], hv1) + dot4(wh[3][2], hv2) + dot4(wh[3][3], hv3);

        // 4-lane butterfly reduce (groups of 4 consecutive lanes)
        p0 += __shfl_xor(p0, 1); p0 += __shfl_xor(p0, 2);
        p1 += __shfl_xor(p1, 1); p1 += __shfl_xor(p1, 2);
        p2 += __shfl_xor(p2, 1); p2 += __shfl_xor(p2, 2);
        p3 += __shfl_xor(p3, 1); p3 += __shfl_xor(p3, 2);

        // thread t owns gate j == t (j = 4*(t>>2) + (t&3))
        const float v = (q == 0) ? p0 : (q == 1) ? p1 : (q == 2) ? p2 : p3;
        g_lds[t] = v + bsum;
    }

    // ---- head for step u-1 (uses h_{u-1} = hv*, hk_{u-2}) ----
    if (u >= 1 && t < KO4_) {
        float ph = dot4(wk[0], hv0) + dot4(wk[1], hv1)
                 + dot4(wk[2], hv2) + dot4(wk[3], hv3);
        ph += __shfl_xor(ph, 1);
        ph += __shfl_xor(ph, 2);
        const float partner = __shfl_xor(hk, 4);  // hk of the (k, o^1) owner
        if (q == 0) {
            const int o = gb & 1;
            const float h0 = (o == 0) ? hk : partner;
            const float h1 = (o == 0) ? partner : hk;
            const float z = ph + hbsum + whh0 * h0 + whh1 * h1;
            hk = tanh_fast(z);
            if (u == len) {  // hk now == hk_{len-1}: emit output
                const int k = gb >> 1;
                out[(k * B_ + b) * H2_ + o] = sigm(hk);
            }
        }
    }

    __syncthreads();  // gates visible; head done with hv buffer

    // ---- cell update on wave 2 (threads 128..191 own cells 0..63) ----
    if (do_lstm && (t >= 128 && t < 192)) {
        const int m = t - 128;
        const float gi = g_lds[m];
        const float gf = g_lds[64 + m];
        const float gg = g_lds[128 + m];
        const float go = g_lds[192 + m];
        c = sigm(gf) * c + sigm(gi) * tanh_fast(gg);
        const float hnew = sigm(go) * tanh_fast(c);
        h_lds[u & 1][m] = hnew;
    }
    __syncthreads();  // h_u visible for next iteration
}

__global__ __launch_bounds__(NTHR, 1)
void lstm_fused(const float* __restrict__ x,       // (B,S,E)
                const int* __restrict__ lengths,   // (B,)
                const float* __restrict__ Wih,     // (256,128)
                const float* __restrict__ Whh,     // (256,64)
                const float* __restrict__ bih,     // (256,)
                const float* __restrict__ bhh,     // (256,)
                const float* __restrict__ hWih,    // (13,2,64)
                const float* __restrict__ hWhh,    // (13,2,2)
                const float* __restrict__ hbih,    // (13,2)
                const float* __restrict__ hbhh,    // (13,2)
                float* __restrict__ out)           // (13,256,2)
{
    const int b = blockIdx.x;
    const int t = threadIdx.x;
    const int q = t & 3;
    const int gb = t >> 2;

    int len = lengths[b];
    len = (len < 1) ? 1 : (len > S_ ? S_ : len);

    __shared__ __align__(16) float h_lds[2][H_];
    __shared__ __align__(16) float g_lds[G_];

    // ---- load this thread's weight slices into registers ----
    float4 wx[4][8];   // Wih[4 gates][quarter q: 32 floats]
    float4 wh[4][4];   // Whh[4 gates][quarter q: 16 floats]
    #pragma unroll
    for (int i = 0; i < 4; ++i) {
        const int j = gb * 4 + i;
        const float4* wr = (const float4*)(Wih + j * E_ + q * 32);
        #pragma unroll
        for (int e = 0; e < 8; ++e) wx[i][e] = wr[e];
        const float4* hr = (const float4*)(Whh + j * H_ + q * 16);
        #pragma unroll
        for (int e = 0; e < 4; ++e) wh[i][e] = hr[e];
    }
    const float bsum = bih[t] + bhh[t];

    // ---- head weight slices (threads 0..103; ko = t>>2 in [0,26)) ----
    float4 wk[4] = {};
    float whh0 = 0.f, whh1 = 0.f, hbsum = 0.f;
    if (t < KO4_) {
        const float4* kr = (const float4*)(hWih + gb * H_ + q * 16);
        #pragma unroll
        for (int e = 0; e < 4; ++e) wk[e] = kr[e];
        whh0 = hWhh[gb * 2 + 0];
        whh1 = hWhh[gb * 2 + 1];
        hbsum = hbih[gb] + hbhh[gb];
    }

    float hk = 0.f;  // head state, owned by lanes t%4==0, t<104
    float c = 0.f;   // cell state, owned by threads 128..191

    if (t < H_) h_lds[1][t] = 0.f;  // h_{-1} = 0 (parity (0+1)&1 == 1)
    __syncthreads();

    // ---- initial x_0 load ----
    const float4* xp0 = (const float4*)(x + (size_t)b * S_ * E_ + q * 32);
    float4 xa[8], xb[8];
    #pragma unroll
    for (int e = 0; e < 8; ++e) xa[e] = xp0[e];

    // ---- main recurrence: u = 0..len (u==len runs the lagged final head) ----
    int u = 0;
    while (true) {
        lstm_step(u, len, t, q, gb, b, wx, wh, wk, whh0, whh1, hbsum, bsum,
                  hk, c, xa, xb, xp0, h_lds, g_lds, out);
        if (u == len) break;
        ++u;
        lstm_step(u, len, t, q, gb, b, wx, wh, wk, whh0, whh1, hbsum, bsum,
                  hk, c, xb, xa, xp0, h_lds, g_lds, out);
        if (u == len) break;
        ++u;
    }
}

}  // namespace

extern "C" void kernel_launch(void* const* d_in, const int* in_sizes, int n_in,
                              void* d_out, int out_size, void* d_ws, size_t ws_size,
                              hipStream_t stream) {
    const float* x    = (const float*)d_in[0];
    const int*   len  = (const int*)d_in[1];
    const float* Wih  = (const float*)d_in[2];
    const float* Whh  = (const float*)d_in[3];
    const float* bih  = (const float*)d_in[4];
    const float* bhh  = (const float*)d_in[5];
    const float* hWih = (const float*)d_in[6];
    const float* hWhh = (const float*)d_in[7];
    const float* hbih = (const float*)d_in[8];
    const float* hbhh = (const float*)d_in[9];
    float* out = (float*)d_out;

    hipLaunchKernelGGL(lstm_fused, dim3(B_), dim3(NTHR), 0, stream,
                       x, len, Wih, Whh, bih, bhh, hWih, hWhh, hbih, hbhh, out);
}

// Round 2
// 3269.952 us; speedup vs baseline: 1.4343x; 1.4343x over previous
//
#include <hip/hip_runtime.h>
#include <cstddef>

// LSTM_27934467293427 — fused persistent-recurrence kernel, R2.
// R1 failure mode: compiler rematerialized weight loads into the step loop
// (VGPR_Count=168 < ~280 needed, no scratch writes) -> ~23 TB/s L2 traffic,
// L2-BW + latency bound. Fix: pin weights in VGPRs via empty asm (cannot be
// rematerialized), 512 thr/block (2 thr/gate, 96 weight floats/thread,
// fits 256-VGPR cap at 2 waves/SIMD), x_t staged through LDS broadcast.

namespace {

constexpr int B_ = 256;
constexpr int S_ = 2048;
constexpr int E_ = 128;
constexpr int H_ = 64;
constexpr int G_ = 256;   // 4*H
constexpr int H2_ = 2;
constexpr int NTHR = 512;
constexpr int KO4_ = 104; // 26 head outputs * 4 lanes

__device__ __forceinline__ float sigm(float x) {
    return __builtin_amdgcn_rcpf(1.0f + __expf(-x));
}
__device__ __forceinline__ float tanh_fast(float x) {
    return 1.0f - 2.0f * __builtin_amdgcn_rcpf(1.0f + __expf(2.0f * x));
}
__device__ __forceinline__ float dot4(float4 a, float4 b) {
    return a.x * b.x + a.y * b.y + a.z * b.z + a.w * b.w;
}
// Opaque register pin: asm-defined values cannot be rematerialized from memory.
#define PIN4(v) asm volatile("" : "+v"(v.x), "+v"(v.y), "+v"(v.z), "+v"(v.w))

__global__ __launch_bounds__(NTHR, 2)
void lstm_fused(const float* __restrict__ x,       // (B,S,E)
                const int* __restrict__ lengths,   // (B,)
                const float* __restrict__ Wih,     // (256,128)
                const float* __restrict__ Whh,     // (256,64)
                const float* __restrict__ bih,     // (256,)
                const float* __restrict__ bhh,     // (256,)
                const float* __restrict__ hWih,    // (13,2,64)
                const float* __restrict__ hWhh,    // (13,2,2)
                const float* __restrict__ hbih,    // (13,2)
                const float* __restrict__ hbhh,    // (13,2)
                float* __restrict__ out)           // (13,256,2)
{
    const int b = blockIdx.x;
    const int t = threadIdx.x;
    const int g = t >> 1;   // gate owned (with partner t^1)
    const int m = t & 1;    // half of the 192-long dot

    int len = lengths[b];
    len = (len < 1) ? 1 : (len > S_ ? S_ : len);

    __shared__ __align__(16) float x_lds[2][E_];
    __shared__ __align__(16) float h_lds[2][H_];
    __shared__ __align__(16) float g_lds[G_];

    // ---- weight slices into registers, pinned ----
    float4 wx[16];  // Wih[g][m*64 .. m*64+63]
    float4 wh[8];   // Whh[g][m*32 .. m*32+31]
    {
        const float4* wr = (const float4*)(Wih + g * E_ + m * 64);
        #pragma unroll
        for (int i = 0; i < 16; ++i) wx[i] = wr[i];
        const float4* hr = (const float4*)(Whh + g * H_ + m * 32);
        #pragma unroll
        for (int i = 0; i < 8; ++i) wh[i] = hr[i];
    }
    #pragma unroll
    for (int i = 0; i < 16; ++i) PIN4(wx[i]);
    #pragma unroll
    for (int i = 0; i < 8; ++i) PIN4(wh[i]);

    const float bsum = (m == 0) ? (bih[g] + bhh[g]) : 0.f;

    // ---- head slices (threads 0..103) ----
    const int q = t & 3, gb = t >> 2;
    float4 wk[4] = {};
    float whh0 = 0.f, whh1 = 0.f, hbsum = 0.f;
    if (t < KO4_) {
        const float4* kr = (const float4*)(hWih + gb * H_ + q * 16);
        #pragma unroll
        for (int e = 0; e < 4; ++e) wk[e] = kr[e];
        whh0 = hWhh[gb * 2 + 0];
        whh1 = hWhh[gb * 2 + 1];
        hbsum = hbih[gb] + hbhh[gb];
    }
    #pragma unroll
    for (int e = 0; e < 4; ++e) PIN4(wk[e]);

    float hk = 0.f;  // head state (lanes q==0, t<104)
    float c = 0.f;   // cell state (threads 256..319)

    // ---- x staging (threads 384..511 own one x element each) ----
    const int tx = t - 384;
    const float* xb_ptr = x + (size_t)b * S_ * E_;
    float xrA = 0.f, xrB = 0.f;
    if (tx >= 0) {
        x_lds[0][tx] = xb_ptr[tx];                       // x_0
        if (1 < len) xrA = xb_ptr[E_ + tx];              // x_1 in flight
    }
    if (t < H_) h_lds[1][t] = 0.f;  // h_{-1}=0 at parity (0+1)&1
    __syncthreads();

    auto step = [&](int u, float xcur, float& xnew) {
        // -- prefetch x_{u+2}; stage x_{u+1} (buffer (u+1)&1 was consumed at u-1) --
        if (tx >= 0) {
            if (u + 2 < len) xnew = xb_ptr[(size_t)(u + 2) * E_ + tx];
            if (u + 1 < len) x_lds[(u + 1) & 1][tx] = xcur;
        }
        // -- gate half-dots (96 FMA/thread), pair-reduce, stage to g_lds --
        if (u < len) {
            const float4* xs = (const float4*)(x_lds[u & 1] + (m << 6));
            const float4* hs = (const float4*)(h_lds[(u + 1) & 1] + (m << 5));
            float pa = 0.f, pb = 0.f;
            #pragma unroll
            for (int i = 0; i < 8; ++i) {
                pa += dot4(wx[2 * i],     xs[2 * i]);
                pb += dot4(wx[2 * i + 1], xs[2 * i + 1]);
            }
            #pragma unroll
            for (int i = 0; i < 4; ++i) {
                pa += dot4(wh[2 * i],     hs[2 * i]);
                pb += dot4(wh[2 * i + 1], hs[2 * i + 1]);
            }
            float p = pa + pb;
            p += __shfl_xor(p, 1);
            if (m == 0) g_lds[g] = p + bsum;
        }
        __syncthreads();  // gates visible

        // -- cell update (wave 4: threads 256..319), writes h_u --
        if (u < len && t >= 256 && t < 320) {
            const int mc = t - 256;
            const float gi = g_lds[mc];
            const float gf = g_lds[64 + mc];
            const float gg = g_lds[128 + mc];
            const float go = g_lds[192 + mc];
            c = sigm(gf) * c + sigm(gi) * tanh_fast(gg);
            h_lds[u & 1][mc] = sigm(go) * tanh_fast(c);
        }
        // -- head for step u-1 (reads h_{u-1} from the OTHER h buffer) --
        if (u >= 1 && t < KO4_) {
            const float4* hh = (const float4*)h_lds[(u + 1) & 1];
            float ph = dot4(wk[0], hh[q * 4 + 0]) + dot4(wk[1], hh[q * 4 + 1])
                     + dot4(wk[2], hh[q * 4 + 2]) + dot4(wk[3], hh[q * 4 + 3]);
            ph += __shfl_xor(ph, 1);
            ph += __shfl_xor(ph, 2);
            const float partner = __shfl_xor(hk, 4);
            if (q == 0) {
                const int o = gb & 1;
                const float h0 = (o == 0) ? hk : partner;
                const float h1 = (o == 0) ? partner : hk;
                hk = tanh_fast(ph + hbsum + whh0 * h0 + whh1 * h1);
                if (u == len) {
                    out[((gb >> 1) * B_ + b) * H2_ + o] = sigm(hk);
                }
            }
        }
        __syncthreads();  // h_u visible for next step
    };

    int u = 0;
    while (true) {
        step(u, xrA, xrB);
        if (u == len) break;
        ++u;
        step(u, xrB, xrA);
        if (u == len) break;
        ++u;
    }
}

}  // namespace

extern "C" void kernel_launch(void* const* d_in, const int* in_sizes, int n_in,
                              void* d_out, int out_size, void* d_ws, size_t ws_size,
                              hipStream_t stream) {
    const float* x    = (const float*)d_in[0];
    const int*   len  = (const int*)d_in[1];
    const float* Wih  = (const float*)d_in[2];
    const float* Whh  = (const float*)d_in[3];
    const float* bih  = (const float*)d_in[4];
    const float* bhh  = (const float*)d_in[5];
    const float* hWih = (const float*)d_in[6];
    const float* hWhh = (const float*)d_in[7];
    const float* hbih = (const float*)d_in[8];
    const float* hbhh = (const float*)d_in[9];
    float* out = (float*)d_out;

    hipLaunchKernelGGL(lstm_fused, dim3(B_), dim3(NTHR), 0, stream,
                       x, len, Wih, Whh, bih, bhh, hWih, hWhh, hbih, hbhh, out);
}